// Round 4
// baseline (76.507 us; speedup 1.0000x reference)
//
#include <hip/hip_runtime.h>

#define B_DIM 512
#define D_DIM 512
#define O_DIM 512
#define KSPLIT 16
#define DCHUNK 32

// logits[b,o] = sum_d [ x*( (-ic)*x + 2*mu*ic ) ] + (-sum_d mu^2*ic)
// Main: grid 512 = (ks 0..15)x(ob 0..7)x(bb 0..3); tile 128b x 64o x 32d,
// 256 thr (4 waves of 64b x 32o), 8x4 micro-tile/lane (16 ds_read_b128 per
// 256 FMAs). Partials -> ws[bid][128][64]; reduce sums 16 splits. No atomics.

__global__ __launch_bounds__(256, 2)
void gda_main(const float* __restrict__ x,
              const float* __restrict__ mu,
              const float* __restrict__ ic,
              float* __restrict__ ws) {
    __shared__ float4 lds_x[128 * 9];         // [b][g], row stride 9 float4
    __shared__ float4 lds_a[64 * 9];          // a' = -ic
    __shared__ float4 lds_b[64 * 9];          // b' = 2*mu*ic
    __shared__ float  lds_cp[64 * 9];         // mu^2*ic float4-sums, padded
    __shared__ float  lds_c[64];              // -sum over this d-range

    const int tid = threadIdx.x;
    const int bid = blockIdx.x;
    const int bb = bid & 3, ob = (bid >> 2) & 7, ks = bid >> 5;
    const int b0 = bb * 128, o0 = ob * 64, d0 = ks * DCHUNK;

    // ---- stage: coalesced global loads, fused transform ----
    const int g   = tid & 7;                  // float4 col 0..7 (32 d)
    const int row = tid >> 3;                 // 0..31
#pragma unroll
    for (int i = 0; i < 4; ++i) {             // x: 128 rows
        const int r = row + 32 * i;
        lds_x[r * 9 + g] = *(const float4*)&x[(b0 + r) * D_DIM + d0 + g * 4];
    }
#pragma unroll
    for (int i = 0; i < 2; ++i) {             // mu/ic: 64 rows
        const int r = row + 32 * i;
        const float4 m4 = *(const float4*)&mu[(o0 + r) * D_DIM + d0 + g * 4];
        const float4 c4 = *(const float4*)&ic[(o0 + r) * D_DIM + d0 + g * 4];
        float4 a4, b4;
        a4.x = -c4.x;              a4.y = -c4.y;
        a4.z = -c4.z;              a4.w = -c4.w;
        b4.x = 2.0f * m4.x * c4.x; b4.y = 2.0f * m4.y * c4.y;
        b4.z = 2.0f * m4.z * c4.z; b4.w = 2.0f * m4.w * c4.w;
        lds_a[r * 9 + g] = a4;
        lds_b[r * 9 + g] = b4;
        lds_cp[r * 9 + g] = m4.x * m4.x * c4.x + m4.y * m4.y * c4.y
                          + m4.z * m4.z * c4.z + m4.w * m4.w * c4.w;
    }
    __syncthreads();

    // per-o constant for this d-range (consumed after the 2nd barrier)
    if (tid < 64) {
        float s = 0.0f;
#pragma unroll
        for (int q = 0; q < 8; ++q) s += lds_cp[tid * 9 + q];
        lds_c[tid] = -s;
    }

    // ---- compute: 4 waves of 64b x 32o; 8x4 micro-tile per lane ----
    const int w    = tid >> 6;
    const int lane = tid & 63;
    const int cb   = lane >> 3;               // b-sub 0..7 (rows wb+cb+8k)
    const int r8   = lane & 7;                // o-sub 0..7 (rows wo+r8+8j)
    const int wb   = (w & 1) * 64, wo = (w >> 1) * 32;

    const float4* xb = &lds_x[(wb + cb) * 9];   // + k*72 + gg
    const float4* ap = &lds_a[(wo + r8) * 9];   // + j*72 + gg
    const float4* bp = &lds_b[(wo + r8) * 9];

    float acc[32];
#pragma unroll
    for (int q = 0; q < 32; ++q) acc[q] = 0.0f;

#pragma unroll
    for (int gg = 0; gg < 8; ++gg) {
        float4 xr[8];
#pragma unroll
        for (int k = 0; k < 8; ++k) xr[k] = xb[k * 72 + gg];
#pragma unroll
        for (int j = 0; j < 4; ++j) {
            const float4 a4 = ap[j * 72 + gg];
            const float4 b4 = bp[j * 72 + gg];
#pragma unroll
            for (int k = 0; k < 8; ++k) {
                float t = acc[k * 4 + j];
                float u;
                u = fmaf(a4.x, xr[k].x, b4.x);  t = fmaf(u, xr[k].x, t);
                u = fmaf(a4.y, xr[k].y, b4.y);  t = fmaf(u, xr[k].y, t);
                u = fmaf(a4.z, xr[k].z, b4.z);  t = fmaf(u, xr[k].z, t);
                u = fmaf(a4.w, xr[k].w, b4.w);  t = fmaf(u, xr[k].w, t);
                acc[k * 4 + j] = t;
            }
        }
    }
    __syncthreads();                          // lds_c ready

    // ---- epilogue: partials (+ per-o constant) to workspace ----
    float* wsb = ws + (size_t)bid * 8192;     // [128 b][64 o]
#pragma unroll
    for (int j = 0; j < 4; ++j) {
        const float cc = lds_c[wo + r8 + 8 * j];
#pragma unroll
        for (int k = 0; k < 8; ++k)
            wsb[(wb + cb + 8 * k) * 64 + (wo + r8 + 8 * j)] = acc[k * 4 + j] + cc;
    }
}

__global__ __launch_bounds__(256, 4)
void gda_reduce(const float* __restrict__ ws, float* __restrict__ out) {
    const int fid = blockIdx.x * 256 + threadIdx.x;   // float4 output index
    const int b   = fid >> 7;                         // 128 float4 per b-row
    const int o4  = fid & 127;
    const int ob  = o4 >> 4, ol4 = o4 & 15;
    const int bbv = b >> 7, bl = b & 127;
    const float* base = ws + ((bbv + 4 * ob) * 8192 + bl * 64 + ol4 * 4);
    float4 s = {0.0f, 0.0f, 0.0f, 0.0f};
#pragma unroll
    for (int k = 0; k < KSPLIT; ++k) {
        const float4 v = *(const float4*)(base + (size_t)k * 262144);
        s.x += v.x; s.y += v.y; s.z += v.z; s.w += v.w;
    }
    ((float4*)out)[fid] = s;
}

extern "C" void kernel_launch(void* const* d_in, const int* in_sizes, int n_in,
                              void* d_out, int out_size, void* d_ws, size_t ws_size,
                              hipStream_t stream) {
    const float* x  = (const float*)d_in[0];
    const float* mu = (const float*)d_in[1];
    const float* ic = (const float*)d_in[2];
    float* ws  = (float*)d_ws;
    float* out = (float*)d_out;

    gda_main  <<<dim3(512), dim3(256), 0, stream>>>(x, mu, ic, ws);
    gda_reduce<<<dim3(256), dim3(256), 0, stream>>>(ws, out);
}